// Round 8
// baseline (533.581 us; speedup 1.0000x reference)
//
#include <hip/hip_runtime.h>

typedef __attribute__((ext_vector_type(8))) short short8;
typedef __attribute__((ext_vector_type(8))) unsigned short ushort8;
typedef __attribute__((ext_vector_type(4))) float f32x4;

#define B_   32
#define L_   8192
#define IN_  512
#define HID_ 512
#define D3_  128

static __device__ __forceinline__ short f2bf(float f) {
    return __builtin_bit_cast(short, (__bf16)f);
}
static __device__ __forceinline__ unsigned short f2bfu(float f) {
    return __builtin_bit_cast(unsigned short, (__bf16)f);
}

// ---- prep: Wh (f32, D3 x HID) -> bf16 bits in ws ----
__global__ void prep_whb(const float* __restrict__ wh, unsigned short* __restrict__ whb) {
    int i = (blockIdx.x * 256 + threadIdx.x) * 4;   // 65536 elems / 4
    float4 f = *(const float4*)(wh + i);
    whb[i + 0] = f2bfu(f.x);
    whb[i + 1] = f2bfu(f.y);
    whb[i + 2] = f2bfu(f.z);
    whb[i + 3] = f2bfu(f.w);
}

// ---- prep: qpb[b][d] = inputs[b] . Wi[d] + bi[d] + bh[d]  (fp32) ----
__global__ void prep_qpb(const float* __restrict__ inputs, const float* __restrict__ Wi,
                         const float* __restrict__ bi, const float* __restrict__ bh,
                         float* __restrict__ qpb) {
    int b = blockIdx.x;
    int d = threadIdx.x;                 // 128 threads
    float acc = bi[d] + bh[d];
    const float* xr = inputs + b * IN_;
    const float* wr = Wi + d * IN_;
    #pragma unroll 4
    for (int i = 0; i < IN_; i += 4) {
        float4 x = *(const float4*)(xr + i);
        float4 w = *(const float4*)(wr + i);
        acc += x.x * w.x + x.y * w.y + x.z * w.z + x.w * w.w;
    }
    qpb[b * D3_ + d] = acc;
}

// ---- main ----
// Lessons: R7 (barriers) lost to R6 (barrier-free) -> keep waves decoupled.
// R6's limiter was depth (1 chunk in flight/wave, loaded HBM latency ~4600cy).
// R8: context prefetch in REGISTERS, depth-2 named ring (16 VGPRs only --
// R5's spill was the 32-VGPR depth-4 ring). Each chunk is issued 2 full
// steps before use: no-stall iff latency <= 2*T; T settles at the BW floor.
// Wh stays fully LDS-resident (128 KiB, XOR-swizzled, 2-way-free reads).
// Zero barriers, zero inline asm -- compiler places counted vmcnt waits.
// Live VGPRs ~90 < 128 cap (R3-proven ballpark, no spill).
__global__ __launch_bounds__(512) void attn_main(
    const float* __restrict__ ctx, const unsigned short* __restrict__ whb,
    const float* __restrict__ qpb, const float* __restrict__ V,
    float* __restrict__ out)
{
    __shared__ unsigned short whs[D3_ * HID_];   // 128 KiB

    const int tid = threadIdx.x;

    // stage Wh^bf16 into LDS, swizzled: 16B slot s of col c stored at s ^ (c&7)
    #pragma unroll
    for (int p = 0; p < 16; ++p) {
        int m = p * 512 + tid;           // 16B-chunk id: col = m>>6, slot = m&63
        int c = m >> 6;
        int s = m & 63;
        ushort8 v = *(const ushort8*)(whb + (size_t)m * 8);
        *(ushort8*)((char*)whs + c * 1024 + (((s ^ (c & 7)) << 4))) = v;
    }
    __syncthreads();

    const int lane = tid & 63;
    const int w    = tid >> 6;           // wave 0..7, owns 16 rows per tile
    const int cb   = lane & 15;          // A-row / C-col index
    const int g    = lane >> 4;          // k-group 0..3
    const int sw   = cb & 7;             // whs swizzle key
    const char* bbase = (const char*)whs + cb * 1024;

    const int b = blockIdx.x >> 3;       // 1024 rows per block, 8 blocks per batch

    float vv[8], qv[8];
    #pragma unroll
    for (int nt = 0; nt < 8; ++nt) {
        vv[nt] = V[nt * 16 + cb];
        qv[nt] = qpb[b * D3_ + nt * 16 + cb];
    }

    // this lane's stream: row (base + cb), 8 floats at g*8, +32 per K-step
    const float* pBase0 = ctx + ((size_t)blockIdx.x * 1024 + w * 16 + cb) * (size_t)HID_ + g * 8;

// one K-step: consume chunk KK from (PA,PB), prefetch chunk KK+2 into the
// same named pair (WAR resolved by sequential semantics), 8 MFMAs from LDS-B.
#define DOSTEP(PA, PB, KK) { \
    short8 aA; \
    aA[0] = f2bf(PA.x); aA[1] = f2bf(PA.y); aA[2] = f2bf(PA.z); aA[3] = f2bf(PA.w); \
    aA[4] = f2bf(PB.x); aA[5] = f2bf(PB.y); aA[6] = f2bf(PB.z); aA[7] = f2bf(PB.w); \
    if ((KK) < 14) { \
        PA = *(const float4*)(pT + ((KK) + 2) * 32); \
        PB = *(const float4*)(pT + ((KK) + 2) * 32 + 4); \
    } else { \
        PA = *(const float4*)(pN + ((KK) - 14) * 32); \
        PB = *(const float4*)(pN + ((KK) - 14) * 32 + 4); \
    } \
    const int o_ = ((((KK) * 4 + g) ^ sw) << 4); \
    _Pragma("unroll") \
    for (int nt = 0; nt < 8; ++nt) { \
        const short8 bb = *(const short8*)(bbase + nt * 16384 + o_); \
        acc[nt] = __builtin_amdgcn_mfma_f32_16x16x32_bf16(aA, bb, acc[nt], 0, 0, 0); \
    } }

    float4 P0a = *(const float4*)(pBase0);
    float4 P0b = *(const float4*)(pBase0 + 4);
    float4 P1a = *(const float4*)(pBase0 + 32);
    float4 P1b = *(const float4*)(pBase0 + 36);

    const float* pT = pBase0;

    #pragma unroll 1
    for (int t = 0; t < 8; ++t) {        // 8 tiles of 128 rows
        // next-tile base for the cross-boundary prefetch; clamp to own block
        // start at t=7 (harmless warm re-read; avoids OOB past ctx end)
        const float* pN = (t < 7) ? (pT + 128 * HID_) : pBase0;

        f32x4 acc[8];
        #pragma unroll
        for (int nt = 0; nt < 8; ++nt) acc[nt] = (f32x4){0.f, 0.f, 0.f, 0.f};

        DOSTEP(P0a, P0b, 0)
        DOSTEP(P1a, P1b, 1)
        DOSTEP(P0a, P0b, 2)
        DOSTEP(P1a, P1b, 3)
        DOSTEP(P0a, P0b, 4)
        DOSTEP(P1a, P1b, 5)
        DOSTEP(P0a, P0b, 6)
        DOSTEP(P1a, P1b, 7)
        DOSTEP(P0a, P0b, 8)
        DOSTEP(P1a, P1b, 9)
        DOSTEP(P0a, P0b, 10)
        DOSTEP(P1a, P1b, 11)
        DOSTEP(P0a, P0b, 12)
        DOSTEP(P1a, P1b, 13)
        DOSTEP(P0a, P0b, 14)
        DOSTEP(P1a, P1b, 15)

        // epilogue: tanh(acc + q) . V, reduce over the 16 cb lanes
        float s0 = 0.f, s1 = 0.f, s2 = 0.f, s3 = 0.f;
        #pragma unroll
        for (int nt = 0; nt < 8; ++nt) {
            const float q = qv[nt], vn = vv[nt];
            s0 += (1.f - 2.f / (__expf(2.f * (acc[nt][0] + q)) + 1.f)) * vn;
            s1 += (1.f - 2.f / (__expf(2.f * (acc[nt][1] + q)) + 1.f)) * vn;
            s2 += (1.f - 2.f / (__expf(2.f * (acc[nt][2] + q)) + 1.f)) * vn;
            s3 += (1.f - 2.f / (__expf(2.f * (acc[nt][3] + q)) + 1.f)) * vn;
        }
        #pragma unroll
        for (int m = 1; m < 16; m <<= 1) {
            s0 += __shfl_xor(s0, m, 64);
            s1 += __shfl_xor(s1, m, 64);
            s2 += __shfl_xor(s2, m, 64);
            s3 += __shfl_xor(s3, m, 64);
        }
        if (cb == 0) {
            const size_t row0 = (size_t)blockIdx.x * 1024 + (size_t)t * 128 + w * 16;
            const size_t off_ = row0 + (size_t)g * 4;
            *(float4*)(out + off_) = make_float4(s0, s1, s2, s3);
            *(float4*)(out + (size_t)B_ * L_ + off_) = make_float4(1.f, 1.f, 1.f, 1.f);
        }
        pT = pN;
    }
#undef DOSTEP
}

extern "C" void kernel_launch(void* const* d_in, const int* in_sizes, int n_in,
                              void* d_out, int out_size, void* d_ws, size_t ws_size,
                              hipStream_t stream) {
    const float* inputs  = (const float*)d_in[0];   // (32, 512)
    const float* context = (const float*)d_in[1];   // (32, 8192, 512)
    const float* Wi      = (const float*)d_in[2];   // (128, 512)
    const float* bi      = (const float*)d_in[3];   // (128,)
    const float* Wh      = (const float*)d_in[4];   // (128, 512)
    const float* bh      = (const float*)d_in[5];   // (128,)
    const float* V       = (const float*)d_in[6];   // (128,)
    float* out = (float*)d_out;                     // [att_row 262144][att 262144]

    unsigned short* whb = (unsigned short*)d_ws;                   // 128 KiB
    float* qpb = (float*)((char*)d_ws + (size_t)D3_ * HID_ * 2);   // 16 KiB

    prep_whb<<<64, 256, 0, stream>>>(Wh, whb);
    prep_qpb<<<B_, D3_, 0, stream>>>(inputs, Wi, bi, bh, qpb);
    attn_main<<<256, 512, 0, stream>>>(context, whb, qpb, V, out);
}

// Round 9
// 131.995 us; speedup vs baseline: 4.0424x; 4.0424x over previous
//
#include <hip/hip_runtime.h>

typedef __attribute__((ext_vector_type(8))) short short8;
typedef __attribute__((ext_vector_type(8))) unsigned short ushort8;
typedef __attribute__((ext_vector_type(4))) float f32x4;

#define B_   32
#define L_   8192
#define IN_  512
#define HID_ 512
#define D3_  128

static __device__ __forceinline__ short f2bf(float f) {
    return __builtin_bit_cast(short, (__bf16)f);
}
static __device__ __forceinline__ unsigned short f2bfu(float f) {
    return __builtin_bit_cast(unsigned short, (__bf16)f);
}

// async global->LDS, 16B per lane (dest = wave-uniform base + lane*16; the
// global SOURCE is per-lane -- R6-validated idiom)
static __device__ __forceinline__ void gload_lds16(const void* g, void* l) {
    __builtin_amdgcn_global_load_lds(
        (const __attribute__((address_space(1))) unsigned int*)g,
        (__attribute__((address_space(3))) unsigned int*)l, 16, 0, 0);
}

// ---- prep: Wh (f32, D3 x HID) -> bf16, PRE-PERMUTED to MFMA lane order ----
// unit u = ks*512 + nt*64 + lane holds Wh[nt*16 + (lane&15)][ks*32 + (lane>>4)*8 .. +8]
// so the kernel's B-read is ds_read_b128 at whs + ks*8192 + nt*1024 + lane*16:
// a contiguous 1 KiB wave access = bank-conflict-free (2 lanes/bank, free).
__global__ void prep_whb2(const float* __restrict__ wh, unsigned short* __restrict__ whb2) {
    int u = blockIdx.x * 256 + threadIdx.x;   // 0..8191 (16B units)
    int lane = u & 63;
    int nt   = (u >> 6) & 7;
    int ks   = u >> 9;
    int col  = nt * 16 + (lane & 15);
    int k0   = ks * 32 + (lane >> 4) * 8;
    const float* src = wh + col * HID_ + k0;
    float4 a = *(const float4*)(src);
    float4 b = *(const float4*)(src + 4);
    unsigned short* d = whb2 + (size_t)u * 8;
    d[0] = f2bfu(a.x); d[1] = f2bfu(a.y); d[2] = f2bfu(a.z); d[3] = f2bfu(a.w);
    d[4] = f2bfu(b.x); d[5] = f2bfu(b.y); d[6] = f2bfu(b.z); d[7] = f2bfu(b.w);
}

// ---- prep: qpb[b][d] = inputs[b] . Wi[d] + bi[d] + bh[d]  (fp32) ----
__global__ void prep_qpb(const float* __restrict__ inputs, const float* __restrict__ Wi,
                         const float* __restrict__ bi, const float* __restrict__ bh,
                         float* __restrict__ qpb) {
    int b = blockIdx.x;
    int d = threadIdx.x;                 // 128 threads
    float acc = bi[d] + bh[d];
    const float* xr = inputs + b * IN_;
    const float* wr = Wi + d * IN_;
    #pragma unroll 4
    for (int i = 0; i < IN_; i += 4) {
        float4 x = *(const float4*)(xr + i);
        float4 w = *(const float4*)(wr + i);
        acc += x.x * w.x + x.y * w.y + x.z * w.z + x.w * w.w;
    }
    qpb[b * D3_ + d] = acc;
}

// ---- main ----
// Structure = R6 (DMA-to-LDS, wave-private chunks, zero barriers, vmcnt(2),
// no register prefetch state -> no spill). ONLY change: LDS layouts are
// lane-linear so every ds_read_b128 is a contiguous 1 KiB wave access.
// R6's reads were 8-way bank-conflicted on BOTH A and B (column stride
// 1024B/128B == 0 mod bank cycle -> slot XOR couldn't spread banks), making
// it LDS-bound at ~2800 cyc/round vs the 1560-cyc HBM floor.
//   B: whs[ks][nt][lane*16]   (pre-permuted in prep_whb2; staging = linear copy)
//   A: cbuf chunk [i][lane*16] with per-lane-permuted DMA source:
//      lane L sources row (L&15), bytes (L>>4)*32 + i*16  (rule #21).
//      A-read address == lane's own DMA dest: conflict-free by construction.
__global__ __launch_bounds__(512) void attn_main(
    const float* __restrict__ ctx, const unsigned short* __restrict__ whb2,
    const float* __restrict__ qpb, const float* __restrict__ V,
    float* __restrict__ out)
{
    __shared__ unsigned short whs[D3_ * HID_];   // 128 KiB: [ks 16][nt 8][1024B]
    __shared__ float cbuf[2][4096];              // 32 KiB: [par][wave 8][i 2][1024B]

    const int tid = threadIdx.x;

    // stage whs: pure linear copy (whb2 already permuted) -- conflict-free
    #pragma unroll
    for (int p = 0; p < 16; ++p) {
        int m = p * 512 + tid;
        *(ushort8*)((char*)whs + (size_t)m * 16) = *(const ushort8*)(whb2 + (size_t)m * 8);
    }
    __syncthreads();

    const int lane = tid & 63;
    const int w    = tid >> 6;           // wave 0..7, owns 16 rows per tile
    const int cb   = lane & 15;          // A-row / C-col index
    const int g    = lane >> 4;          // k-group 0..3

    // B-read base (lane-linear)
    const char* bptr = (const char*)whs + lane * 16;

    // A DMA: per-lane source and wave-private LDS dest (lane-linear)
    const char* gsrc = (const char*)(ctx
        + ((size_t)blockIdx.x * 1024 + w * 16 + (lane & 15)) * (size_t)HID_)
        + (lane >> 4) * 32;
    char* ldst = (char*)cbuf + w * 2048 + lane * 16;
    // A-read: same address pattern as the DMA dest
    const char* aptr = (const char*)cbuf + w * 2048 + lane * 16;

    const int b = blockIdx.x >> 3;       // 1024 rows per block, 8 blocks per batch

    float vv[8], qv[8];
    #pragma unroll
    for (int nt = 0; nt < 8; ++nt) {
        vv[nt] = V[nt * 16 + cb];
        qv[nt] = qpb[b * D3_ + nt * 16 + cb];
    }

#define STAGE(CC) { \
    const char* g0_ = gsrc + (size_t)((CC) >> 4) * (128 * HID_ * 4) + ((CC) & 15) * 128; \
    char* l0_ = ldst + (((CC) & 1) ? 16384 : 0); \
    gload_lds16(g0_, l0_); \
    gload_lds16(g0_ + 16, l0_ + 1024); }

    STAGE(0)
    STAGE(1)

    #pragma unroll 1
    for (int t = 0; t < 8; ++t) {        // 8 tiles of 128 rows
        f32x4 acc[8];
        #pragma unroll
        for (int nt = 0; nt < 8; ++nt) acc[nt] = (f32x4){0.f, 0.f, 0.f, 0.f};

        #pragma unroll
        for (int kk = 0; kk < 16; ++kk) {
            const int c = t * 16 + kk;
            if (c < 127) asm volatile("s_waitcnt vmcnt(2)" ::: "memory");
            else         asm volatile("s_waitcnt vmcnt(0)" ::: "memory");

            const char* ap = aptr + ((c & 1) ? 16384 : 0);
            const f32x4 a0 = *(const f32x4*)(ap);           // k-slot 2g
            const f32x4 a1 = *(const f32x4*)(ap + 1024);    // k-slot 2g+1
            short8 aA;
            aA[0] = f2bf(a0[0]); aA[1] = f2bf(a0[1]); aA[2] = f2bf(a0[2]); aA[3] = f2bf(a0[3]);
            aA[4] = f2bf(a1[0]); aA[5] = f2bf(a1[1]); aA[6] = f2bf(a1[2]); aA[7] = f2bf(a1[3]);

            const char* bp = bptr + kk * 8192;
            #pragma unroll
            for (int nt = 0; nt < 8; ++nt) {
                const short8 bb = *(const short8*)(bp + nt * 1024);
                acc[nt] = __builtin_amdgcn_mfma_f32_16x16x32_bf16(aA, bb, acc[nt], 0, 0, 0);
            }
            // A-reads must complete before DMA may overwrite this buffer
            asm volatile("s_waitcnt lgkmcnt(0)" ::: "memory");

            if (kk == 15) {
                // epilogue: tanh(acc + q) . V, reduce over the 16 cb lanes
                float s0 = 0.f, s1 = 0.f, s2 = 0.f, s3 = 0.f;
                #pragma unroll
                for (int nt = 0; nt < 8; ++nt) {
                    const float q = qv[nt], vn = vv[nt];
                    s0 += (1.f - 2.f / (__expf(2.f * (acc[nt][0] + q)) + 1.f)) * vn;
                    s1 += (1.f - 2.f / (__expf(2.f * (acc[nt][1] + q)) + 1.f)) * vn;
                    s2 += (1.f - 2.f / (__expf(2.f * (acc[nt][2] + q)) + 1.f)) * vn;
                    s3 += (1.f - 2.f / (__expf(2.f * (acc[nt][3] + q)) + 1.f)) * vn;
                }
                #pragma unroll
                for (int m = 1; m < 16; m <<= 1) {
                    s0 += __shfl_xor(s0, m, 64);
                    s1 += __shfl_xor(s1, m, 64);
                    s2 += __shfl_xor(s2, m, 64);
                    s3 += __shfl_xor(s3, m, 64);
                }
                if (cb == 0) {
                    const size_t row0 = (size_t)blockIdx.x * 1024 + (size_t)t * 128 + w * 16;
                    const size_t off_ = row0 + (size_t)g * 4;
                    *(float4*)(out + off_) = make_float4(s0, s1, s2, s3);
                    *(float4*)(out + (size_t)B_ * L_ + off_) = make_float4(1.f, 1.f, 1.f, 1.f);
                }
            }
            if (c + 2 < 128) STAGE(c + 2)
        }
    }
#undef STAGE
}

extern "C" void kernel_launch(void* const* d_in, const int* in_sizes, int n_in,
                              void* d_out, int out_size, void* d_ws, size_t ws_size,
                              hipStream_t stream) {
    const float* inputs  = (const float*)d_in[0];   // (32, 512)
    const float* context = (const float*)d_in[1];   // (32, 8192, 512)
    const float* Wi      = (const float*)d_in[2];   // (128, 512)
    const float* bi      = (const float*)d_in[3];   // (128,)
    const float* Wh      = (const float*)d_in[4];   // (128, 512)
    const float* bh      = (const float*)d_in[5];   // (128,)
    const float* V       = (const float*)d_in[6];   // (128,)
    float* out = (float*)d_out;                     // [att_row 262144][att 262144]

    unsigned short* whb2 = (unsigned short*)d_ws;                  // 128 KiB (permuted)
    float* qpb = (float*)((char*)d_ws + (size_t)D3_ * HID_ * 2);   // 16 KiB

    prep_whb2<<<32, 256, 0, stream>>>(Wh, whb2);
    prep_qpb<<<B_, D3_, 0, stream>>>(inputs, Wi, bi, bh, qpb);
    attn_main<<<256, 512, 0, stream>>>(context, whb2, qpb, V, out);
}

// Round 10
// 125.927 us; speedup vs baseline: 4.2372x; 1.0482x over previous
//
#include <hip/hip_runtime.h>

typedef __attribute__((ext_vector_type(8))) short short8;
typedef __attribute__((ext_vector_type(8))) unsigned short ushort8;
typedef __attribute__((ext_vector_type(4))) float f32x4;

#define B_   32
#define L_   8192
#define IN_  512
#define HID_ 512
#define D3_  128

static __device__ __forceinline__ short f2bf(float f) {
    return __builtin_bit_cast(short, (__bf16)f);
}
static __device__ __forceinline__ unsigned short f2bfu(float f) {
    return __builtin_bit_cast(unsigned short, (__bf16)f);
}

// async global->LDS, 16B per lane (dest = wave-uniform base + lane*16; the
// global SOURCE is per-lane -- R6-validated idiom)
static __device__ __forceinline__ void gload_lds16(const void* g, void* l) {
    __builtin_amdgcn_global_load_lds(
        (const __attribute__((address_space(1))) unsigned int*)g,
        (__attribute__((address_space(3))) unsigned int*)l, 16, 0, 0);
}

// ---- prep: Wh (f32, D3 x HID) -> bf16, PRE-PERMUTED to MFMA lane order ----
// unit u = ks*512 + nt*64 + lane holds Wh[nt*16 + (lane&15)][ks*32 + (lane>>4)*8 .. +8]
// so the kernel's B-read is ds_read_b128 at whs + ks*8192 + nt*1024 + lane*16:
// a contiguous 1 KiB wave access = bank-conflict-free.
__global__ void prep_whb2(const float* __restrict__ wh, unsigned short* __restrict__ whb2) {
    int u = blockIdx.x * 256 + threadIdx.x;   // 0..8191 (16B units)
    int lane = u & 63;
    int nt   = (u >> 6) & 7;
    int ks   = u >> 9;
    int col  = nt * 16 + (lane & 15);
    int k0   = ks * 32 + (lane >> 4) * 8;
    const float* src = wh + col * HID_ + k0;
    float4 a = *(const float4*)(src);
    float4 b = *(const float4*)(src + 4);
    unsigned short* d = whb2 + (size_t)u * 8;
    d[0] = f2bfu(a.x); d[1] = f2bfu(a.y); d[2] = f2bfu(a.z); d[3] = f2bfu(a.w);
    d[4] = f2bfu(b.x); d[5] = f2bfu(b.y); d[6] = f2bfu(b.z); d[7] = f2bfu(b.w);
}

// ---- prep: qpb[b][d] = inputs[b] . Wi[d] + bi[d] + bh[d]  (fp32) ----
__global__ void prep_qpb(const float* __restrict__ inputs, const float* __restrict__ Wi,
                         const float* __restrict__ bi, const float* __restrict__ bh,
                         float* __restrict__ qpb) {
    int b = blockIdx.x;
    int d = threadIdx.x;                 // 128 threads
    float acc = bi[d] + bh[d];
    const float* xr = inputs + b * IN_;
    const float* wr = Wi + d * IN_;
    #pragma unroll 4
    for (int i = 0; i < IN_; i += 4) {
        float4 x = *(const float4*)(xr + i);
        float4 w = *(const float4*)(wr + i);
        acc += x.x * w.x + x.y * w.y + x.z * w.z + x.w * w.w;
    }
    qpb[b * D3_ + d] = acc;
}

// ---- main ----
// Structure = R9 (DMA-to-LDS, wave-private chunks, zero barriers, lane-linear
// conflict-free LDS, no register prefetch state -> no spill).
// ONE change: the STAGE for chunk c+2 is issued at the TOP of the step --
// right after the 2 A-reads of the buffer it overwrites drain (targeted
// lgkmcnt(0)) -- instead of after all MFMAs. R6/R9 issued it at step END,
// making land(c+2) = S(c) + T + Lat, i.e. effective pipeline depth 1 and
// T >= Lat (~2440 cyc observed). Now 2T >= Lat + ~200 -> T at the ~1525-cyc
// HBM BW floor. sched_barrier(0) pins the STAGE placement (rule #18).
__global__ __launch_bounds__(512) void attn_main(
    const float* __restrict__ ctx, const unsigned short* __restrict__ whb2,
    const float* __restrict__ qpb, const float* __restrict__ V,
    float* __restrict__ out)
{
    __shared__ unsigned short whs[D3_ * HID_];   // 128 KiB: [ks 16][nt 8][1024B]
    __shared__ float cbuf[2][4096];              // 32 KiB: [par][wave 8][i 2][1024B]

    const int tid = threadIdx.x;

    // stage whs: pure linear copy (whb2 already permuted) -- conflict-free
    #pragma unroll
    for (int p = 0; p < 16; ++p) {
        int m = p * 512 + tid;
        *(ushort8*)((char*)whs + (size_t)m * 16) = *(const ushort8*)(whb2 + (size_t)m * 8);
    }
    __syncthreads();

    const int lane = tid & 63;
    const int w    = tid >> 6;           // wave 0..7, owns 16 rows per tile
    const int cb   = lane & 15;          // A-row / C-col index
    const int g    = lane >> 4;          // k-group 0..3

    // B-read base (lane-linear)
    const char* bptr = (const char*)whs + lane * 16;

    // A DMA: per-lane source and wave-private LDS dest (lane-linear)
    const char* gsrc = (const char*)(ctx
        + ((size_t)blockIdx.x * 1024 + w * 16 + (lane & 15)) * (size_t)HID_)
        + (lane >> 4) * 32;
    char* ldst = (char*)cbuf + w * 2048 + lane * 16;
    // A-read: same address pattern as the DMA dest
    const char* aptr = (const char*)cbuf + w * 2048 + lane * 16;

    const int b = blockIdx.x >> 3;       // 1024 rows per block, 8 blocks per batch

    float vv[8], qv[8];
    #pragma unroll
    for (int nt = 0; nt < 8; ++nt) {
        vv[nt] = V[nt * 16 + cb];
        qv[nt] = qpb[b * D3_ + nt * 16 + cb];
    }

#define STAGE(CC) { \
    const char* g0_ = gsrc + (size_t)((CC) >> 4) * (128 * HID_ * 4) + ((CC) & 15) * 128; \
    char* l0_ = ldst + (((CC) & 1) ? 16384 : 0); \
    gload_lds16(g0_, l0_); \
    gload_lds16(g0_ + 16, l0_ + 1024); }

    STAGE(0)
    STAGE(1)

    #pragma unroll 1
    for (int t = 0; t < 8; ++t) {        // 8 tiles of 128 rows
        f32x4 acc[8];
        #pragma unroll
        for (int nt = 0; nt < 8; ++nt) acc[nt] = (f32x4){0.f, 0.f, 0.f, 0.f};

        #pragma unroll
        for (int kk = 0; kk < 16; ++kk) {
            const int c = t * 16 + kk;
            if (c < 127) asm volatile("s_waitcnt vmcnt(2)" ::: "memory");
            else         asm volatile("s_waitcnt vmcnt(0)" ::: "memory");

            // A-reads of the buffer that chunk c+2 will overwrite
            const char* ap = aptr + ((c & 1) ? 16384 : 0);
            const f32x4 a0 = *(const f32x4*)(ap);           // k-slot 2g
            const f32x4 a1 = *(const f32x4*)(ap + 1024);    // k-slot 2g+1
            // drain ONLY those 2 reads, then issue the DMA immediately --
            // the stage must sit at the TOP of the step, not after the MFMAs
            asm volatile("s_waitcnt lgkmcnt(0)" ::: "memory");
            __builtin_amdgcn_sched_barrier(0);
            if (c + 2 < 128) STAGE(c + 2)
            __builtin_amdgcn_sched_barrier(0);

            short8 aA;
            aA[0] = f2bf(a0[0]); aA[1] = f2bf(a0[1]); aA[2] = f2bf(a0[2]); aA[3] = f2bf(a0[3]);
            aA[4] = f2bf(a1[0]); aA[5] = f2bf(a1[1]); aA[6] = f2bf(a1[2]); aA[7] = f2bf(a1[3]);

            const char* bp = bptr + kk * 8192;
            #pragma unroll
            for (int nt = 0; nt < 8; ++nt) {
                const short8 bb = *(const short8*)(bp + nt * 1024);
                acc[nt] = __builtin_amdgcn_mfma_f32_16x16x32_bf16(aA, bb, acc[nt], 0, 0, 0);
            }

            if (kk == 15) {
                // epilogue: tanh(acc + q) . V, reduce over the 16 cb lanes
                // (runs AFTER the next tile's first stages -- overlapped)
                float s0 = 0.f, s1 = 0.f, s2 = 0.f, s3 = 0.f;
                #pragma unroll
                for (int nt = 0; nt < 8; ++nt) {
                    const float q = qv[nt], vn = vv[nt];
                    s0 += (1.f - 2.f / (__expf(2.f * (acc[nt][0] + q)) + 1.f)) * vn;
                    s1 += (1.f - 2.f / (__expf(2.f * (acc[nt][1] + q)) + 1.f)) * vn;
                    s2 += (1.f - 2.f / (__expf(2.f * (acc[nt][2] + q)) + 1.f)) * vn;
                    s3 += (1.f - 2.f / (__expf(2.f * (acc[nt][3] + q)) + 1.f)) * vn;
                }
                #pragma unroll
                for (int m = 1; m < 16; m <<= 1) {
                    s0 += __shfl_xor(s0, m, 64);
                    s1 += __shfl_xor(s1, m, 64);
                    s2 += __shfl_xor(s2, m, 64);
                    s3 += __shfl_xor(s3, m, 64);
                }
                if (cb == 0) {
                    const size_t row0 = (size_t)blockIdx.x * 1024 + (size_t)t * 128 + w * 16;
                    const size_t off_ = row0 + (size_t)g * 4;
                    *(float4*)(out + off_) = make_float4(s0, s1, s2, s3);
                    *(float4*)(out + (size_t)B_ * L_ + off_) = make_float4(1.f, 1.f, 1.f, 1.f);
                }
            }
        }
    }
#undef STAGE
}

extern "C" void kernel_launch(void* const* d_in, const int* in_sizes, int n_in,
                              void* d_out, int out_size, void* d_ws, size_t ws_size,
                              hipStream_t stream) {
    const float* inputs  = (const float*)d_in[0];   // (32, 512)
    const float* context = (const float*)d_in[1];   // (32, 8192, 512)
    const float* Wi      = (const float*)d_in[2];   // (128, 512)
    const float* bi      = (const float*)d_in[3];   // (128,)
    const float* Wh      = (const float*)d_in[4];   // (128, 512)
    const float* bh      = (const float*)d_in[5];   // (128,)
    const float* V       = (const float*)d_in[6];   // (128,)
    float* out = (float*)d_out;                     // [att_row 262144][att 262144]

    unsigned short* whb2 = (unsigned short*)d_ws;                  // 128 KiB (permuted)
    float* qpb = (float*)((char*)d_ws + (size_t)D3_ * HID_ * 2);   // 16 KiB

    prep_whb2<<<32, 256, 0, stream>>>(Wh, whb2);
    prep_qpb<<<B_, D3_, 0, stream>>>(inputs, Wi, bi, bh, qpb);
    attn_main<<<256, 512, 0, stream>>>(context, whb2, qpb, V, out);
}

// Round 11
// 124.643 us; speedup vs baseline: 4.2809x; 1.0103x over previous
//
#include <hip/hip_runtime.h>

typedef __attribute__((ext_vector_type(8))) short short8;
typedef __attribute__((ext_vector_type(8))) unsigned short ushort8;
typedef __attribute__((ext_vector_type(4))) float f32x4;

#define B_   32
#define L_   8192
#define IN_  512
#define HID_ 512
#define D3_  128

static __device__ __forceinline__ short f2bf(float f) {
    return __builtin_bit_cast(short, (__bf16)f);
}
static __device__ __forceinline__ unsigned short f2bfu(float f) {
    return __builtin_bit_cast(unsigned short, (__bf16)f);
}

// async global->LDS, 16B per lane (dest = wave-uniform base + lane*16; the
// global SOURCE is per-lane -- R6-validated idiom)
static __device__ __forceinline__ void gload_lds16(const void* g, void* l) {
    __builtin_amdgcn_global_load_lds(
        (const __attribute__((address_space(1))) unsigned int*)g,
        (__attribute__((address_space(3))) unsigned int*)l, 16, 0, 0);
}

// ---- prep: Wh (f32, D3 x HID) -> bf16, PRE-PERMUTED to MFMA lane order ----
__global__ void prep_whb2(const float* __restrict__ wh, unsigned short* __restrict__ whb2) {
    int u = blockIdx.x * 256 + threadIdx.x;   // 0..8191 (16B units)
    int lane = u & 63;
    int nt   = (u >> 6) & 7;
    int ks   = u >> 9;
    int col  = nt * 16 + (lane & 15);
    int k0   = ks * 32 + (lane >> 4) * 8;
    const float* src = wh + col * HID_ + k0;
    float4 a = *(const float4*)(src);
    float4 b = *(const float4*)(src + 4);
    unsigned short* d = whb2 + (size_t)u * 8;
    d[0] = f2bfu(a.x); d[1] = f2bfu(a.y); d[2] = f2bfu(a.z); d[3] = f2bfu(a.w);
    d[4] = f2bfu(b.x); d[5] = f2bfu(b.y); d[6] = f2bfu(b.z); d[7] = f2bfu(b.w);
}

// ---- prep: qpb[b][d] = inputs[b] . Wi[d] + bi[d] + bh[d]  (fp32) ----
__global__ void prep_qpb(const float* __restrict__ inputs, const float* __restrict__ Wi,
                         const float* __restrict__ bi, const float* __restrict__ bh,
                         float* __restrict__ qpb) {
    int b = blockIdx.x;
    int d = threadIdx.x;                 // 128 threads
    float acc = bi[d] + bh[d];
    const float* xr = inputs + b * IN_;
    const float* wr = Wi + d * IN_;
    #pragma unroll 4
    for (int i = 0; i < IN_; i += 4) {
        float4 x = *(const float4*)(xr + i);
        float4 w = *(const float4*)(wr + i);
        acc += x.x * w.x + x.y * w.y + x.z * w.z + x.w * w.w;
    }
    qpb[b * D3_ + d] = acc;
}

// ---- main ----
// Structure = R10 (DMA-to-LDS, wave-private chunks, zero barriers, stage at
// top of step, depth-2 vmcnt(2) ring, no register prefetch state).
// ONE change: the DMA source permutation is SECTOR-DENSE. R9/R10's pattern
// (lane L: row L&15, byte (L>>4)*32) made every gload_lds instruction touch
// 16 rows x 2 HALF-sectors -- each 64B sector requested by BOTH instructions
// of the pair => ~2x CU<->L2 request traffic, capping data BW at ~4.2 TB/s
// regardless of scheduling (why R9/R10 were neutral). Now each instruction
// reads 8 rows x full 128B (2 complete sectors/row, 100% utilization):
//   instr1: lane L -> row (L>>3),   piece (L&7)^(L>>3)   -> slots 0..63
//   instr2: lane L -> row 8+(L>>3), piece (L&7)^(L>>3)   -> slots 64..127
// The baked XOR keeps A-reads bank-conflict-free despite the 128B row
// stride: read slot (cb,g) = (cb>>3)*1024+(cb&7)*128+((2g)^(cb&7))*16;
// per 8-lane phase group quads = 2g^cb = 8 distinct (m136/m201 criterion).
__global__ __launch_bounds__(512) void attn_main(
    const float* __restrict__ ctx, const unsigned short* __restrict__ whb2,
    const float* __restrict__ qpb, const float* __restrict__ V,
    float* __restrict__ out)
{
    __shared__ unsigned short whs[D3_ * HID_];   // 128 KiB: [ks 16][nt 8][1024B]
    __shared__ float cbuf[2][4096];              // 32 KiB: [par][wave 8][2048B]

    const int tid = threadIdx.x;

    // stage whs: pure linear copy (whb2 already permuted) -- conflict-free
    #pragma unroll
    for (int p = 0; p < 16; ++p) {
        int m = p * 512 + tid;
        *(ushort8*)((char*)whs + (size_t)m * 16) = *(const ushort8*)(whb2 + (size_t)m * 8);
    }
    __syncthreads();

    const int lane = tid & 63;
    const int w    = tid >> 6;           // wave 0..7, owns 16 rows per tile
    const int cb   = lane & 15;          // A-row / C-col index
    const int g    = lane >> 4;          // k-group 0..3

    // B-read base (lane-linear)
    const char* bptr = (const char*)whs + lane * 16;

    // A DMA: sector-dense per-lane source; lane-linear LDS dest
    const int srow = lane >> 3;                      // row-in-8 this lane sources
    const int spce = (lane & 7) ^ srow;              // piece (16B) within 128B
    const float* gsrcA = ctx
        + ((size_t)blockIdx.x * 1024 + w * 16 + srow) * (size_t)HID_ + spce * 4;
    const float* gsrcB = gsrcA + 8 * HID_;           // rows 8..15
    char* ldst = (char*)cbuf + w * 2048 + lane * 16;

    // A-read: row cb, pieces 2g / 2g+1, through the baked XOR
    const char* abase = (const char*)cbuf + w * 2048 + (cb >> 3) * 1024 + (cb & 7) * 128;
    const int aoff0 = (((2 * g)     ^ (cb & 7)) << 4);
    const int aoff1 = (((2 * g + 1) ^ (cb & 7)) << 4);

    const int b = blockIdx.x >> 3;       // 1024 rows per block, 8 blocks per batch

    float vv[8], qv[8];
    #pragma unroll
    for (int nt = 0; nt < 8; ++nt) {
        vv[nt] = V[nt * 16 + cb];
        qv[nt] = qpb[b * D3_ + nt * 16 + cb];
    }

#define STAGE(CC) { \
    const size_t go_ = (size_t)((CC) >> 4) * (128 * HID_) + ((CC) & 15) * 32; \
    char* l0_ = ldst + (((CC) & 1) ? 16384 : 0); \
    gload_lds16(gsrcA + go_, l0_); \
    gload_lds16(gsrcB + go_, l0_ + 1024); }

    STAGE(0)
    STAGE(1)

    #pragma unroll 1
    for (int t = 0; t < 8; ++t) {        // 8 tiles of 128 rows
        f32x4 acc[8];
        #pragma unroll
        for (int nt = 0; nt < 8; ++nt) acc[nt] = (f32x4){0.f, 0.f, 0.f, 0.f};

        #pragma unroll
        for (int kk = 0; kk < 16; ++kk) {
            const int c = t * 16 + kk;
            if (c < 127) asm volatile("s_waitcnt vmcnt(2)" ::: "memory");
            else         asm volatile("s_waitcnt vmcnt(0)" ::: "memory");

            // A-reads of the buffer that chunk c+2 will overwrite
            const char* ap = abase + ((c & 1) ? 16384 : 0);
            const f32x4 a0 = *(const f32x4*)(ap + aoff0);   // pieces 2g
            const f32x4 a1 = *(const f32x4*)(ap + aoff1);   // pieces 2g+1
            // drain ONLY those 2 reads, then issue the DMA immediately
            asm volatile("s_waitcnt lgkmcnt(0)" ::: "memory");
            __builtin_amdgcn_sched_barrier(0);
            if (c + 2 < 128) STAGE(c + 2)
            __builtin_amdgcn_sched_barrier(0);

            short8 aA;
            aA[0] = f2bf(a0[0]); aA[1] = f2bf(a0[1]); aA[2] = f2bf(a0[2]); aA[3] = f2bf(a0[3]);
            aA[4] = f2bf(a1[0]); aA[5] = f2bf(a1[1]); aA[6] = f2bf(a1[2]); aA[7] = f2bf(a1[3]);

            const char* bp = bptr + kk * 8192;
            #pragma unroll
            for (int nt = 0; nt < 8; ++nt) {
                const short8 bb = *(const short8*)(bp + nt * 1024);
                acc[nt] = __builtin_amdgcn_mfma_f32_16x16x32_bf16(aA, bb, acc[nt], 0, 0, 0);
            }

            if (kk == 15) {
                // epilogue: tanh(acc + q) . V, reduce over the 16 cb lanes
                float s0 = 0.f, s1 = 0.f, s2 = 0.f, s3 = 0.f;
                #pragma unroll
                for (int nt = 0; nt < 8; ++nt) {
                    const float q = qv[nt], vn = vv[nt];
                    s0 += (1.f - 2.f / (__expf(2.f * (acc[nt][0] + q)) + 1.f)) * vn;
                    s1 += (1.f - 2.f / (__expf(2.f * (acc[nt][1] + q)) + 1.f)) * vn;
                    s2 += (1.f - 2.f / (__expf(2.f * (acc[nt][2] + q)) + 1.f)) * vn;
                    s3 += (1.f - 2.f / (__expf(2.f * (acc[nt][3] + q)) + 1.f)) * vn;
                }
                #pragma unroll
                for (int m = 1; m < 16; m <<= 1) {
                    s0 += __shfl_xor(s0, m, 64);
                    s1 += __shfl_xor(s1, m, 64);
                    s2 += __shfl_xor(s2, m, 64);
                    s3 += __shfl_xor(s3, m, 64);
                }
                if (cb == 0) {
                    const size_t row0 = (size_t)blockIdx.x * 1024 + (size_t)t * 128 + w * 16;
                    const size_t off_ = row0 + (size_t)g * 4;
                    *(float4*)(out + off_) = make_float4(s0, s1, s2, s3);
                    *(float4*)(out + (size_t)B_ * L_ + off_) = make_float4(1.f, 1.f, 1.f, 1.f);
                }
            }
        }
    }
#undef STAGE
}

extern "C" void kernel_launch(void* const* d_in, const int* in_sizes, int n_in,
                              void* d_out, int out_size, void* d_ws, size_t ws_size,
                              hipStream_t stream) {
    const float* inputs  = (const float*)d_in[0];   // (32, 512)
    const float* context = (const float*)d_in[1];   // (32, 8192, 512)
    const float* Wi      = (const float*)d_in[2];   // (128, 512)
    const float* bi      = (const float*)d_in[3];   // (128,)
    const float* Wh      = (const float*)d_in[4];   // (128, 512)
    const float* bh      = (const float*)d_in[5];   // (128,)
    const float* V       = (const float*)d_in[6];   // (128,)
    float* out = (float*)d_out;                     // [att_row 262144][att 262144]

    unsigned short* whb2 = (unsigned short*)d_ws;                  // 128 KiB (permuted)
    float* qpb = (float*)((char*)d_ws + (size_t)D3_ * HID_ * 2);   // 16 KiB

    prep_whb2<<<32, 256, 0, stream>>>(Wh, whb2);
    prep_qpb<<<B_, D3_, 0, stream>>>(inputs, Wi, bi, bh, qpb);
    attn_main<<<256, 512, 0, stream>>>(context, whb2, qpb, V, out);
}